// Round 1
// baseline (367.165 us; speedup 1.0000x reference)
//
#include <hip/hip_runtime.h>

// Problem: B=32, S=8192, D=256, K=64
//   idx = top_k(attention[b,:], 64) (descending value, ties -> lower index first)
//   out[b,k,:] = context[b, idx[b,k], :]
//
// Strategy: 1 block per batch, 256 threads. Each thread owns S/256 = 32
// attention values in registers as sortable u64 keys:
//   key = (monotonic_u32(value) << 32) | (S-1-idx)
// so unsigned max == (larger value, then smaller index). 64 iterations of
// block-wide argmax; winner key zeroed in-place (unrolled, register-resident).
// Then coalesced float4 gather of the 64 selected rows.

constexpr int BATCH = 32;
constexpr int S = 8192;
constexpr int D = 256;
constexpr int K = 64;
constexpr int THREADS = 256;
constexpr int VPT = S / THREADS; // 32 values per thread

__device__ __forceinline__ unsigned int mono_key(float f) {
    unsigned int u = __float_as_uint(f);
    // order-preserving map float -> u32 (works for +/-, inf; no NaNs in input)
    return (u & 0x80000000u) ? ~u : (u | 0x80000000u);
}

__device__ __forceinline__ unsigned long long umax64(unsigned long long a,
                                                     unsigned long long b) {
    return a > b ? a : b;
}

__global__ __launch_bounds__(THREADS) void topk_gather_kernel(
    const float* __restrict__ att,   // [B, S]
    const float* __restrict__ ctx,   // [B, S, D]
    float* __restrict__ out)         // [B, K, D]
{
    const int b   = blockIdx.x;
    const int tid = threadIdx.x;

    // ---- load + encode keys (coalesced: lane i reads att[b, tid + j*256]) ----
    unsigned long long key[VPT];
    const float* arow = att + (size_t)b * S;
#pragma unroll
    for (int j = 0; j < VPT; ++j) {
        int idx = tid + j * THREADS;
        float v = arow[idx];
        key[j] = ((unsigned long long)mono_key(v) << 32) |
                 (unsigned int)(S - 1 - idx);   // smaller idx -> bigger low bits
    }

    __shared__ unsigned long long s_wavemax[THREADS / 64];
    __shared__ int s_idx[K];

    // ---- K iterations of block-wide argmax ----
    for (int k = 0; k < K; ++k) {
        // local max over register-resident keys (fully unrolled)
        unsigned long long lmax = 0ull;
#pragma unroll
        for (int j = 0; j < VPT; ++j) lmax = umax64(lmax, key[j]);

        // wave(64)-level butterfly reduce
#pragma unroll
        for (int off = 32; off > 0; off >>= 1) {
            unsigned long long o = __shfl_xor(lmax, off, 64);
            lmax = umax64(lmax, o);
        }
        if ((tid & 63) == 0) s_wavemax[tid >> 6] = lmax;
        __syncthreads();

        unsigned long long g = umax64(umax64(s_wavemax[0], s_wavemax[1]),
                                      umax64(s_wavemax[2], s_wavemax[3]));
        if (tid == 0) s_idx[k] = S - 1 - (int)(unsigned int)(g & 0xFFFFFFFFull);

        // zero the (unique) winning key; uniform unrolled loop keeps keys in VGPRs
#pragma unroll
        for (int j = 0; j < VPT; ++j) {
            if (key[j] == g) key[j] = 0ull;
        }
        __syncthreads();  // protect s_wavemax reuse next iteration
    }

    // ---- gather: out[b,k,:] = ctx[b, s_idx[k], :], float4-vectorized ----
    const float4* ctx4 = (const float4*)(ctx + (size_t)b * S * D);
    float4*       out4 = (float4*)(out + (size_t)b * K * D);
    constexpr int ROW4 = D / 4;           // 64 float4 per row
    for (int e = tid; e < K * ROW4; e += THREADS) {
        int k = e >> 6;                   // one wave spans exactly one row
        int c = e & (ROW4 - 1);
        out4[e] = ctx4[(size_t)s_idx[k] * ROW4 + c];
    }
}

extern "C" void kernel_launch(void* const* d_in, const int* in_sizes, int n_in,
                              void* d_out, int out_size, void* d_ws, size_t ws_size,
                              hipStream_t stream) {
    const float* att = (const float*)d_in[0];   // [32, 8192] f32
    const float* ctx = (const float*)d_in[1];   // [32, 8192, 256] f32
    // d_in[2] is K (scalar int) == 64, compile-time constant here.
    float* out = (float*)d_out;                 // [32, 64, 256] f32

    topk_gather_kernel<<<BATCH, THREADS, 0, stream>>>(att, ctx, out);
}

// Round 2
// 345.152 us; speedup vs baseline: 1.0638x; 1.0638x over previous
//
#include <hip/hip_runtime.h>

// Problem: B=32, S=8192, D=256, K=64
//   idx = top_k(attention[b,:], 64) (descending value, ties -> lower index first)
//   out[b,k,:] = context[b, idx[b,k], :]
//
// Round 2: cached per-thread top-2 argmax.
// 1 block per batch, 256 threads. Keys: (mono32(v) << 32) | (S-1-idx) -- unsigned
// max == (larger value, then lower index); all keys unique and > 0.
// Each thread caches its top-2 unextracted keys; block argmax reduces only the
// 256 cached maxima (6-step u64 butterfly + 1 barrier/iter via parity-buffered
// wave-max LDS). Winner demotes its cache; on exhaustion it re-streams its 32
// values from L2 and rebuilds top-2 over {key < g} (exact: a thread's
// unextracted keys are all < the key it just had extracted).

constexpr int BATCH   = 32;
constexpr int S       = 8192;
constexpr int D       = 256;
constexpr int K       = 64;
constexpr int THREADS = 256;
constexpr int F4PT    = S / THREADS / 4;   // 8 float4 per thread

__device__ __forceinline__ unsigned int mono_key(float f) {
    unsigned int u = __float_as_uint(f);
    return (u & 0x80000000u) ? ~u : (u | 0x80000000u);  // order-preserving, no NaNs in input
}

__device__ __forceinline__ unsigned long long umax64(unsigned long long a,
                                                     unsigned long long b) {
    return a > b ? a : b;
}

// insert x into sorted top-2 (m0 >= m1), branchless
__device__ __forceinline__ void ins2(unsigned long long x,
                                     unsigned long long& m0,
                                     unsigned long long& m1) {
    bool c0 = x > m0;
    bool c1 = x > m1;
    m1 = c0 ? m0 : (c1 ? x : m1);
    m0 = c0 ? x : m0;
}

__global__ __launch_bounds__(THREADS) void topk_gather_kernel(
    const float* __restrict__ att,   // [B, S]
    const float* __restrict__ ctx,   // [B, S, D]
    float* __restrict__ out)         // [B, K, D]
{
    const int b    = blockIdx.x;
    const int tid  = threadIdx.x;
    const int lane = tid & 63;
    const int wid  = tid >> 6;

    const float4* arow4 = (const float4*)(att + (size_t)b * S);

    // ---- build per-thread top-2 cache (coalesced float4 stream) ----
    unsigned long long m0 = 0ull, m1 = 0ull;  // 0 = -inf sentinel (real keys > 0)
#pragma unroll
    for (int j = 0; j < F4PT; ++j) {
        float4 v = arow4[tid + j * THREADS];
        int base = 4 * (tid + j * THREADS);
        ins2(((unsigned long long)mono_key(v.x) << 32) | (unsigned int)(S - 1 - (base + 0)), m0, m1);
        ins2(((unsigned long long)mono_key(v.y) << 32) | (unsigned int)(S - 1 - (base + 1)), m0, m1);
        ins2(((unsigned long long)mono_key(v.z) << 32) | (unsigned int)(S - 1 - (base + 2)), m0, m1);
        ins2(((unsigned long long)mono_key(v.w) << 32) | (unsigned int)(S - 1 - (base + 3)), m0, m1);
    }
    int vcnt = 2;

    __shared__ unsigned long long s_wm[2][THREADS / 64];
    __shared__ int s_idx[K];

    // ---- K iterations of block argmax over the 256 cached maxima ----
    for (int k = 0; k < K; ++k) {
        unsigned long long w = m0;
#pragma unroll
        for (int off = 32; off > 0; off >>= 1) {
            unsigned long long o = __shfl_xor(w, off, 64);
            w = umax64(w, o);
        }
        if (lane == 0) s_wm[k & 1][wid] = w;
        __syncthreads();   // single barrier per iter; parity buffer prevents WAR on s_wm

        unsigned long long g = umax64(umax64(s_wm[k & 1][0], s_wm[k & 1][1]),
                                      umax64(s_wm[k & 1][2], s_wm[k & 1][3]));
        if (tid == 0) s_idx[k] = S - 1 - (int)(unsigned int)(g & 0xFFFFFFFFull);

        if (m0 == g) {                 // unique winner (keys unique)
            if (vcnt == 2) {
                m0 = m1;               // true 2nd-best becomes max
                vcnt = 1;
            } else {
                // rescan from L2: rebuild top-2 over my keys strictly < g
                m0 = 0ull; m1 = 0ull;
#pragma unroll
                for (int j = 0; j < F4PT; ++j) {
                    float4 v = arow4[tid + j * THREADS];
                    int base = 4 * (tid + j * THREADS);
                    unsigned long long kk;
                    kk = ((unsigned long long)mono_key(v.x) << 32) | (unsigned int)(S - 1 - (base + 0));
                    if (kk < g) ins2(kk, m0, m1);
                    kk = ((unsigned long long)mono_key(v.y) << 32) | (unsigned int)(S - 1 - (base + 1));
                    if (kk < g) ins2(kk, m0, m1);
                    kk = ((unsigned long long)mono_key(v.z) << 32) | (unsigned int)(S - 1 - (base + 2));
                    if (kk < g) ins2(kk, m0, m1);
                    kk = ((unsigned long long)mono_key(v.w) << 32) | (unsigned int)(S - 1 - (base + 3));
                    if (kk < g) ins2(kk, m0, m1);
                }
                vcnt = 2;
            }
        }
    }
    __syncthreads();   // s_idx[63] visibility for gather

    // ---- gather: out[b,k,:] = ctx[b, s_idx[k], :], float4-vectorized ----
    const float4* ctx4 = (const float4*)(ctx + (size_t)b * S * D);
    float4*       out4 = (float4*)(out + (size_t)b * K * D);
    constexpr int ROW4 = D / 4;               // 64 float4 per row
#pragma unroll
    for (int e = tid; e < K * ROW4; e += THREADS) {
        int k = e >> 6;                       // one wave spans exactly one row
        int c = e & (ROW4 - 1);
        out4[e] = ctx4[(size_t)s_idx[k] * ROW4 + c];
    }
}

extern "C" void kernel_launch(void* const* d_in, const int* in_sizes, int n_in,
                              void* d_out, int out_size, void* d_ws, size_t ws_size,
                              hipStream_t stream) {
    const float* att = (const float*)d_in[0];   // [32, 8192] f32
    const float* ctx = (const float*)d_in[1];   // [32, 8192, 256] f32
    // d_in[2] is K (scalar int) == 64, compile-time constant here.
    float* out = (float*)d_out;                 // [32, 64, 256] f32

    topk_gather_kernel<<<BATCH, THREADS, 0, stream>>>(att, ctx, out);
}

// Round 3
// 312.600 us; speedup vs baseline: 1.1745x; 1.1041x over previous
//
#include <hip/hip_runtime.h>

// Problem: B=32, S=8192, D=256, K=64
//   idx = top_k(attention[b,:], 64) (descending, ties -> lower index first)
//   out[b,k,:] = context[b, idx[b,k], :]
//
// Round 3: parallel radix-threshold select + bitonic sort (no serial K-loop).
// Key: (mono32(v) << 32) | (S-1-idx)  -- unsigned compare == (value desc, idx asc).
// 1) 14-bit histogram of key high bits (16384 bins, LDS atomics).
// 2) Parallel suffix scan -> threshold bin T of the 64th largest key.
// 3) Collect candidates (bin >= T), C ~ 75 expected, cap 256.
// 4) 256-wide block bitonic sort (desc) -> threads 0..63 hold top-64 in order.
// 5) Coalesced float4 gather.

constexpr int BATCH   = 32;
constexpr int S       = 8192;
constexpr int D       = 256;
constexpr int K       = 64;
constexpr int THREADS = 256;
constexpr int NBINS   = 16384;   // top 14 bits of mono key
constexpr int CAP     = 256;     // candidate capacity (expected C ~ 75)

__device__ __forceinline__ unsigned int mono_key(float f) {
    unsigned int u = __float_as_uint(f);
    return (u & 0x80000000u) ? ~u : (u | 0x80000000u);  // order-preserving; no NaNs in input
}
__device__ __forceinline__ unsigned long long umax64(unsigned long long a, unsigned long long b) {
    return a > b ? a : b;
}
__device__ __forceinline__ unsigned long long umin64(unsigned long long a, unsigned long long b) {
    return a < b ? a : b;
}

__global__ __launch_bounds__(THREADS) void topk_gather_kernel(
    const float* __restrict__ att,   // [B, S]
    const float* __restrict__ ctx,   // [B, S, D]
    float* __restrict__ out)         // [B, K, D]
{
    const int b    = blockIdx.x;
    const int tid  = threadIdx.x;
    const int lane = tid & 63;
    const int wid  = tid >> 6;

    __shared__ unsigned int       hist[NBINS];              // 64 KB
    __shared__ unsigned long long s_cand[CAP];              // 2 KB
    __shared__ unsigned long long s_sort[THREADS];          // 2 KB
    __shared__ unsigned int       s_wsum[THREADS / 64];
    __shared__ unsigned int       s_cnt, s_chunk, s_above, s_T;
    __shared__ int                s_idx[K];

    // ---- zero histogram (stride-256: 2 lanes/bank, conflict-free) ----
    for (int i = tid; i < NBINS; i += THREADS) hist[i] = 0u;
    if (tid == 0) s_cnt = 0u;
    __syncthreads();

    // ---- load attention row (coalesced float4), cache in VGPRs, histogram ----
    const float4* arow4 = (const float4*)(att + (size_t)b * S);
    float4 f[8];
#pragma unroll
    for (int j = 0; j < 8; ++j) {
        f[j] = arow4[tid + j * THREADS];
        atomicAdd(&hist[mono_key(f[j].x) >> 18], 1u);
        atomicAdd(&hist[mono_key(f[j].y) >> 18], 1u);
        atomicAdd(&hist[mono_key(f[j].z) >> 18], 1u);
        atomicAdd(&hist[mono_key(f[j].w) >> 18], 1u);
    }
    __syncthreads();

    // ---- per-thread chunk sums (64 bins each; rotated uint4 reads vs bank conflicts) ----
    unsigned int mypart = 0;
    {
        const uint4* h4 = (const uint4*)hist;
        int cb = tid * 16;                       // 16 uint4 = 64 bins
#pragma unroll
        for (int j = 0; j < 16; ++j) {
            uint4 u = h4[cb + ((j + tid) & 15)];
            mypart += u.x + u.y + u.z + u.w;
        }
    }

    // ---- inclusive suffix scan over tid (wave shfl_down scan + cross-wave fix) ----
    unsigned int suf = mypart;
#pragma unroll
    for (int off = 1; off < 64; off <<= 1) {
        unsigned int o = __shfl_down(suf, off, 64);
        if (lane + off < 64) suf += o;
    }
    if (lane == 0) s_wsum[wid] = suf;            // wave total
    __syncthreads();
    for (int w = wid + 1; w < THREADS / 64; ++w) suf += s_wsum[w];
    unsigned int sufnext = suf - mypart;         // count strictly above my chunk

    // exactly one owner chunk: suf >= K crosses to sufnext < K
    if (suf >= (unsigned)K && sufnext < (unsigned)K) {
        s_chunk = (unsigned)tid;
        s_above = sufnext;
    }
    __syncthreads();

    // ---- refine threshold bin within owner chunk (wave 0, ballot) ----
    if (wid == 0) {
        int base = (int)s_chunk * 64;
        unsigned int above = s_above;
        unsigned int cf = hist[base + lane];
#pragma unroll
        for (int off = 1; off < 64; off <<= 1) {
            unsigned int o = __shfl_down(cf, off, 64);
            if (lane + off < 64) cf += o;
        }
        // cf = count of keys in bins [base+lane .. base+63]
        unsigned long long mask = __ballot(above + cf >= (unsigned)K);
        if (lane == 0) s_T = (unsigned)(base + 63 - __clzll(mask));  // max bin with suf >= K
    }
    __syncthreads();
    const unsigned int T = s_T;

    // ---- collect candidates: bin >= T (C in [64, 64+threshold_bin_count)) ----
#pragma unroll
    for (int j = 0; j < 8; ++j) {
        int base = 4 * (tid + j * THREADS);
        float v[4] = {f[j].x, f[j].y, f[j].z, f[j].w};
#pragma unroll
        for (int c = 0; c < 4; ++c) {
            unsigned int k32 = mono_key(v[c]);
            if ((k32 >> 18) >= T) {
                unsigned p = atomicAdd(&s_cnt, 1u);
                if (p < (unsigned)CAP)
                    s_cand[p] = ((unsigned long long)k32 << 32) |
                                (unsigned int)(S - 1 - (base + c));
            }
        }
    }
    __syncthreads();

    // ---- 256-wide bitonic sort, descending (pad with 0 < any real key) ----
    unsigned int C = s_cnt;
    unsigned long long key = (tid < (int)C) ? s_cand[tid] : 0ull;

#pragma unroll
    for (int k = 2; k <= THREADS; k <<= 1) {
        for (int j = k >> 1; j > 0; j >>= 1) {
            unsigned long long other;
            if (j < 64) {
                other = __shfl_xor(key, j, 64);
            } else {
                __syncthreads();
                s_sort[tid] = key;
                __syncthreads();
                other = s_sort[tid ^ j];
            }
            bool low     = (tid & j) == 0;
            bool descSeg = (tid & k) == 0;
            key = (low == descSeg) ? umax64(key, other) : umin64(key, other);
        }
    }

    if (tid < K) s_idx[tid] = S - 1 - (int)(unsigned int)(key & 0xFFFFFFFFull);
    __syncthreads();

    // ---- gather: out[b,k,:] = ctx[b, s_idx[k], :], float4-vectorized ----
    const float4* ctx4 = (const float4*)(ctx + (size_t)b * S * D);
    float4*       out4 = (float4*)(out + (size_t)b * K * D);
    constexpr int ROW4 = D / 4;               // 64 float4 per row
#pragma unroll
    for (int e = tid; e < K * ROW4; e += THREADS) {
        int k = e >> 6;                       // one wave spans exactly one row
        int c = e & (ROW4 - 1);
        out4[e] = ctx4[(size_t)s_idx[k] * ROW4 + c];
    }
}

extern "C" void kernel_launch(void* const* d_in, const int* in_sizes, int n_in,
                              void* d_out, int out_size, void* d_ws, size_t ws_size,
                              hipStream_t stream) {
    const float* att = (const float*)d_in[0];   // [32, 8192] f32
    const float* ctx = (const float*)d_in[1];   // [32, 8192, 256] f32
    // d_in[2] is K (scalar int) == 64, compile-time constant here.
    float* out = (float*)d_out;                 // [32, 64, 256] f32

    topk_gather_kernel<<<BATCH, THREADS, 0, stream>>>(att, ctx, out);
}